// Round 11
// baseline (143.985 us; speedup 1.0000x reference)
//
#include <hip/hip_runtime.h>

#define HH 1024
#define WW 1024
#define NIMG 12

// fwd8: F(l) = sum of a over lanes l..l+7   (valid for lane <= 56)
__device__ __forceinline__ float fwd8(float a) {
  a += __shfl_down(a, 1, 64);
  a += __shfl_down(a, 2, 64);
  a += __shfl_down(a, 4, 64);
  return a;
}
// bwd8: B(l) = sum of a over lanes l-7..l (valid for lane >= 7); same balanced
// pairwise tree as fwd8 over the same 8 values -> bitwise-identical result.
__device__ __forceinline__ float bwd8(float a) {
  a += __shfl_up(a, 1, 64);
  a += __shfl_up(a, 2, 64);
  a += __shfl_up(a, 4, 64);
  return a;
}

struct RowLd { float v0, v1, wc; };

// Issue the 3 global loads for row ry (zero padded outside image).
__device__ __forceinline__ RowLd row_load(const float* __restrict__ s, int ry, int col) {
  RowLd t;
  if ((unsigned)ry < (unsigned)HH) {
    const float* r = s + (size_t)ry * WW;
    t.v0 = (col >= 7) ? r[col - 7] : 0.0f;      // x[col-7]
    t.v1 = (col + 7 < WW) ? r[col + 7] : 0.0f;  // x[col+7]
    t.wc = r[col];                              // x[col]
  } else { t.v0 = 0.0f; t.v1 = 0.0f; t.wc = 0.0f; }
  return t;
}

// Shuffle-combine: lh = sum x[col-7..col], rh = sum x[col..col+7], w = x[col]
__device__ __forceinline__ void row_combine(const RowLd& t, int lane,
                                            float& lh, float& rh, float& w) {
  float lf = fwd8(t.v0);
  float lb = bwd8(t.wc);
  bool lo = (lane <= 56);
  lh = lo ? lf : lb;
  float rsh = __shfl_down(lh, 7, 64);   // rh[col] = lh[col+7], bitwise == fwd8(wc)
  float rb  = bwd8(t.v1);
  rh = lo ? rsh : rb;
  w  = t.wc;
}

// first-wins argmin combine: keep a unless |b| strictly smaller (tie -> a).
// Tree of these preserves jnp.argmin first-index semantics exactly.
__device__ __forceinline__ float winner(float a, float b) {
  return (fabsf(b) < fabsf(a)) ? b : a;
}

// Compute one output row given window accumulators and ring slots.
__device__ __forceinline__ float out_px(float ua, float ub, float uc,
                                        float da, float db, float dc,
                                        float lh0, float rh0, float w0) {
  const float ih = 1.0f / 120.0f, iq = 1.0f / 64.0f;
  const float nw0 = -w0;
  const float Ls = ua + da - lh0;   // full 15 rows, left cols
  const float Rs = ub + db - rh0;
  const float Us = ua + ub - uc;    // up 8 rows, full 15 cols
  const float Ds = da + db - dc;
  float d0 = fmaf(Ls, ih, nw0);   // L
  float d1 = fmaf(Rs, ih, nw0);   // R
  float d2 = fmaf(Us, ih, nw0);   // U
  float d3 = fmaf(Ds, ih, nw0);   // D
  float d4 = fmaf(ua, iq, nw0);   // NW
  float d5 = fmaf(ub, iq, nw0);   // NE
  float d6 = fmaf(da, iq, nw0);   // SW
  float d7 = fmaf(db, iq, nw0);   // SE
  // depth-3 first-wins argmin tree (== serial strict-< scan, bitwise)
  float w01 = winner(d0, d1), w23 = winner(d2, d3);
  float w45 = winner(d4, d5), w67 = winner(d6, d7);
  float bd = winner(winner(w01, w23), winner(w45, w67));
  return w0 + bd;
}

// One SWF step. Wave owns a 64-col x 32-row tile; 16-deep register ring of
// (lh, rh, w) rows; vertical 8-windows as sliding sums; TWO rows per inner
// iteration. Row y+8's combine goes to TEMPS and is committed to the ring only
// AFTER the row-y slides, which must still read the old slot (i+8)&15 = row y-8.
__global__ __launch_bounds__(256) void swf_step(const float* __restrict__ src,
                                                float* __restrict__ dst) {
  const int lane = threadIdx.x & 63;
  const int wid  = threadIdx.x >> 6;
  const int col  = blockIdx.x * 64 + lane;             // 16 strips x 64
  const int y0   = (blockIdx.y * 4 + wid) * 32;        // 32 chunks x 32 rows
  const float* s = src + (size_t)blockIdx.z * HH * WW;
  float* d       = dst + (size_t)blockIdx.z * HH * WW;

  float rlh[16], rrh[16], rw[16];

  // Prologue: rows y0-8 .. y0+6 (15 rows) into slot row&15 = (j+8)&15.
  #pragma unroll
  for (int j = 0; j < 15; ++j) {
    const int slot = (j + 8) & 15;
    RowLd t = row_load(s, y0 - 8 + j, col);
    row_combine(t, lane, rlh[slot], rrh[slot], rw[slot]);
  }

  // Sliding-window accumulators for "previous output row" y0-1:
  //   u* over rows y0-8..y0-1 (slots 8..15), d* over rows y0-1..y0+6 (15,0..6)
  float ua = 0.f, ub = 0.f, uc = 0.f, da = 0.f, db = 0.f, dc = 0.f;
  #pragma unroll
  for (int j = 0; j < 8; ++j) {
    const int sl = (8 + j) & 15;
    ua += rlh[sl]; ub += rrh[sl]; uc += rw[sl];
  }
  #pragma unroll
  for (int j = 0; j < 8; ++j) {
    const int sl = (15 + j) & 15;
    da += rlh[sl]; db += rrh[sl]; dc += rw[sl];
  }

  // Load pipe: slot(row) = (row - y0 - 7) & 7. Prime rows y0+7..y0+10.
  RowLd pipe[8];
  #pragma unroll
  for (int k = 0; k < 4; ++k) pipe[k] = row_load(s, y0 + 7 + k, col);

  #pragma unroll 1
  for (int yb = 0; yb < 32; yb += 16) {
    #pragma unroll
    for (int i = 0; i < 16; i += 2) {   // process rows y, y+1 per iteration
      const int y = y0 + yb + i;
      // prefetch rows y+11, y+12 (consumed 2 pairs later); 16%8==0 -> yb drops out
      pipe[(i + 4) & 7] = row_load(s, y + 11, col);
      pipe[(i + 5) & 7] = row_load(s, y + 12, col);

      // combine rows y+7 and y+8 — two independent DS trees in flight.
      // Row y+7 can be committed (slot ls0 held dead row y-9); row y+8 must
      // wait in temps: slot ls1 still holds LIVE row y-8 (read below).
      const int ls0 = (i + 7) & 15;
      const int ls1 = (i + 8) & 15;
      row_combine(pipe[i & 7], lane, rlh[ls0], rrh[ls0], rw[ls0]);
      float lh1, rh1, w1;
      row_combine(pipe[(i + 1) & 7], lane, lh1, rh1, w1);

      // ---- row y: slide windows y-1 -> y (reads OLD slot ls1 = row y-8)
      ua += rlh[i];   ua -= rlh[ls1];
      ub += rrh[i];   ub -= rrh[ls1];
      uc += rw [i];   uc -= rw [ls1];
      da += rlh[ls0]; da -= rlh[(i + 15) & 15];
      db += rrh[ls0]; db -= rrh[(i + 15) & 15];
      dc += rw [ls0]; dc -= rw [(i + 15) & 15];
      const float o0 = out_px(ua, ub, uc, da, db, dc, rlh[i], rrh[i], rw[i]);

      // commit row y+8 into the ring (row y-8 now dead)
      rlh[ls1] = lh1; rrh[ls1] = rh1; rw[ls1] = w1;

      // ---- row y+1: slide windows y -> y+1
      const int i1 = i + 1;
      ua += rlh[i1];  ua -= rlh[(i1 + 8) & 15];
      ub += rrh[i1];  ub -= rrh[(i1 + 8) & 15];
      uc += rw [i1];  uc -= rw [(i1 + 8) & 15];
      da += rlh[ls1]; da -= rlh[i];
      db += rrh[ls1]; db -= rrh[i];
      dc += rw [ls1]; dc -= rw [i];
      const float o1 = out_px(ua, ub, uc, da, db, dc, rlh[i1], rrh[i1], rw[i1]);

      d[(size_t)y * WW + col]       = o0;
      d[(size_t)(y + 1) * WW + col] = o1;
    }
  }
}

extern "C" void kernel_launch(void* const* d_in, const int* in_sizes, int n_in,
                              void* d_out, int out_size, void* d_ws, size_t ws_size,
                              hipStream_t stream) {
  const float* in = (const float*)d_in[0];
  float* out = (float*)d_out;
  float* ws  = (float*)d_ws;   // needs 12*1024*1024*4 = 50.3 MB scratch

  dim3 grid(WW / 64, 8, NIMG);  // 16 col-strips, 8 chunk-groups (x4 waves x 32 rows), 12 planes
  dim3 block(256);

  // iteration = 3 (from setup_inputs), radius = 7 baked in.
  swf_step<<<grid, block, 0, stream>>>(in, out);   // step 1: in  -> out
  swf_step<<<grid, block, 0, stream>>>(out, ws);   // step 2: out -> ws
  swf_step<<<grid, block, 0, stream>>>(ws, out);   // step 3: ws  -> out
}